// Round 7
// baseline (503.582 us; speedup 1.0000x reference)
//
#include <hip/hip_runtime.h>
#include <hip/hip_bf16.h>
#include <cmath>

// ---- problem constants ----
constexpr int cB  = 2;
constexpr int cS  = 1024;
constexpr int cNH = 32;
constexpr int cHD = 128;
constexpr int cHID = 4096;
constexpr int cM  = cB * cS;        // 2048 rows

typedef unsigned short u16;
typedef __bf16 bf16x8 __attribute__((ext_vector_type(8)));
typedef float  f32x4  __attribute__((ext_vector_type(4)));

__device__ __forceinline__ u16 f2b(float f) { return __builtin_bit_cast(u16, (__bf16)f); }

// ---------------- f32 -> bf16, 8 elems/thread ----------------
__global__ void cvt_bf16(const float* __restrict__ in, u16* __restrict__ out, int n8) {
  int i = blockIdx.x * blockDim.x + threadIdx.x;
  if (i >= n8) return;
  const float4* in4 = (const float4*)in;
  float4 a = in4[2 * i], b = in4[2 * i + 1];
  union { u16 u[8]; uint4 v; } r;
  r.u[0] = f2b(a.x); r.u[1] = f2b(a.y); r.u[2] = f2b(a.z); r.u[3] = f2b(a.w);
  r.u[4] = f2b(b.x); r.u[5] = f2b(b.y); r.u[6] = f2b(b.z); r.u[7] = f2b(b.w);
  ((uint4*)out)[i] = r.v;
}

// ---------------- RoPE cos/sin table: [B*S][64] ----------------
__global__ void rope_table_k(const int* __restrict__ pos,
                             float* __restrict__ cosT, float* __restrict__ sinT) {
  int idx = blockIdx.x * blockDim.x + threadIdx.x;   // < B*S*64
  int i = idx & 63, bs = idx >> 6;
  float p = (float)pos[bs];
  float freq = exp2f(-(float)i * (13.287712379549449f / 64.0f));
  float a = p * freq;
  float s, c;
  sincosf(a, &s, &c);
  cosT[idx] = c; sinT[idx] = s;
}

// ---------------- RoPE in-place on Q and K (bf16), interleaved pairs ------
__global__ void rope_apply(u16* __restrict__ Q, u16* __restrict__ Kb,
                           const float* __restrict__ cosT, const float* __restrict__ sinT) {
  int idx = blockIdx.x * blockDim.x + threadIdx.x;
  const int nPer = cB * cS * cNH * (cHD / 8);        // 1,048,576
  u16* P = (idx < nPer) ? Q : Kb;
  int t = (idx < nPer) ? idx : idx - nPer;
  int d8 = t & 15;
  int h  = (t >> 4) & 31;
  int bs = t >> 9;
  size_t base = ((size_t)bs * cNH + h) * cHD + d8 * 8;
  uint4 v = *reinterpret_cast<uint4*>(P + base);
  u16* u = reinterpret_cast<u16*>(&v);
  int pb = bs * 64 + d8 * 4;
  float4 cs = *reinterpret_cast<const float4*>(cosT + pb);
  float4 sn = *reinterpret_cast<const float4*>(sinT + pb);
  float co[4] = {cs.x, cs.y, cs.z, cs.w};
  float si[4] = {sn.x, sn.y, sn.z, sn.w};
#pragma unroll
  for (int p = 0; p < 4; ++p) {
    float e = (float)__builtin_bit_cast(__bf16, u[2 * p]);
    float o = (float)__builtin_bit_cast(__bf16, u[2 * p + 1]);
    float e2 = e * co[p] - o * si[p];
    float o2 = o * co[p] + e * si[p];
    u[2 * p]     = f2b(e2);
    u[2 * p + 1] = f2b(o2);
  }
  *reinterpret_cast<uint4*>(P + base) = v;
}

// ---------------- V [B,S,NH,HD] -> Vt [B*NH, HD, S] ----------------
__global__ void transpose_v(const u16* __restrict__ V, u16* __restrict__ Vt) {
  __shared__ u16 tile[32][33];
  int bh = blockIdx.z;
  int b = bh >> 5, h = bh & 31;
  int s0 = blockIdx.x * 32, d0 = blockIdx.y * 32;
  int tx = threadIdx.x & 31, ty0 = threadIdx.x >> 5;
#pragma unroll
  for (int i = 0; i < 4; ++i) {
    int r = ty0 + i * 8;
    tile[r][tx] = V[((size_t)(b * cS + s0 + r) * cNH + h) * cHD + d0 + tx];
  }
  __syncthreads();
#pragma unroll
  for (int i = 0; i < 4; ++i) {
    int r = ty0 + i * 8;
    Vt[((size_t)bh * cHD + d0 + r) * cS + s0 + tx] = tile[tx][r];
  }
}

// ================= 256x256 8-phase GEMM (T2+T3+T4+T5) =====================
// C[M, Ntot] = A[M,4096] @ [W0;W1;W2]^T (+bias). BK=64, 512 thr = 8 waves
// (2M x 4N -> 128x64 per wave, acc[8][4]). LDS 128 KB:
// sm[2 dbuf][4 units][8192 u16]; unit = 16 KB, kk-major [256 rows][32 k]:
//   u0 = A kk0, u1 = B kk0, u2 = A kk1, u3 = B kk1 (also the stage order).
// Swizzle (both sides, rule 21): read chunk g' = g ^ ((c>>1)&3); staged
// global source column kc' = kc ^ ((row>>1)&3); LDS dest linear.
// 4 phases per K-tile: {8,4,8,4} ds_reads + 1 staged unit + 16 MFMA each,
// dual barriers, lgkmcnt(0)+sched_barrier before MFMA, setprio around MFMA.
// vmcnt(4) ONLY at end-ph1 (drains this tile's kk1 units) and end-ph3
// (drains next tile's kk0 units); >=4 vm instr (1 K-half) always in flight.
// Outstanding-count trace (2 instr per staged unit), steady state:
//   entry: {Akk1_t, Bkk1_t}(4); ph0 +Akk0_{t+1}(6); ph1 +Bkk0_{t+1}(8)
//   -> vmcnt(4) drains kk1_t; ph2 +Akk1'(6); ph3 +Bkk1'(8) -> vmcnt(4)
//   drains kk0_{t+1} = next entry invariant. Last tile peeled (no stages;
//   end-ph1 vmcnt(0) final drain).
// WAR: stages write dbuf^1 (tile t+1) while reads hit dbuf (tile t); the
// previous tenants of dbuf^1 were fully read last iteration (barriers).
// MODE 0: bf16 out + bias. MODE 2: f32 partial, no bias, blockIdx.y k-slice.
// NTX = n-tiles per XCD for the bijective swizzle (48 = 8*6, 16 = 8*2).
template <int MODE, int NTX>
__global__ __launch_bounds__(512, 2)
void gemm256(const u16* __restrict__ A_,
             const u16* __restrict__ W0, const u16* __restrict__ W1,
             const u16* __restrict__ W2,
             const float* __restrict__ b0_, const float* __restrict__ b1_,
             const float* __restrict__ b2_,
             void* o0, void* o1, void* o2, int ktiles) {
  __shared__ __align__(16) u16 sm[2][4][8192];
  const int tid = threadIdx.x, wid = tid >> 6, lane = tid & 63;
  const int c = lane & 15, g = lane >> 4;
  const int wm = wid >> 2, wn = wid & 3;
  const int gsw = (g ^ ((c >> 1) & 3)) * 8;          // lane-constant read swizzle (u16 units)
  const int bid = blockIdx.x;
  const int xcd = bid & 7, j = bid >> 3;
  const int mt = j / NTX, ntl = xcd * NTX + j % NTX;
  const int mrow0 = mt * 256;
  const int gn0 = ntl * 256;
  const int sel = gn0 >> 12;
  const int n0 = gn0 & 4095;
  const u16* Bw = (sel == 0) ? W0 : (sel == 1 ? W1 : W2);
  const int kbase = blockIdx.y * ktiles * 64;

  f32x4 acc[8][4] = {};

#define STG(P, R0, T, KKH, DD, U)                                              \
  {                                                                            \
    _Pragma("unroll") for (int l = 0; l < 2; ++l) {                            \
      int ci = (l * 8 + wid) * 64 + lane;                                      \
      int rw = ci >> 2;                                                        \
      int kc2 = (ci & 3) ^ ((rw >> 1) & 3);                                    \
      __builtin_amdgcn_global_load_lds(                                        \
          (const void*)((P) + (size_t)((R0) + rw) * cHID + kbase + (T) * 64 +  \
                        (KKH) * 32 + kc2 * 8),                                 \
          (void*)(&sm[DD][U][(l * 8 + wid) * 512]), 16, 0, 0);                 \
    }                                                                          \
  }

#define RD_A(dst, MH, UU, DD)                                                  \
  _Pragma("unroll") for (int i = 0; i < 4; ++i) {                              \
    int ra = wm * 128 + (MH) * 64 + i * 16 + c;                                \
    dst[i] = *reinterpret_cast<const bf16x8*>(&sm[DD][UU][ra * 32 + gsw]);     \
  }
#define RD_B(dst, UU, DD)                                                      \
  _Pragma("unroll") for (int i = 0; i < 4; ++i) {                              \
    int rb = wn * 64 + i * 16 + c;                                             \
    dst[i] = *reinterpret_cast<const bf16x8*>(&sm[DD][UU][rb * 32 + gsw]);     \
  }
#define MFMA16(aR, bR, MOFF)                                                   \
  __builtin_amdgcn_s_setprio(1);                                               \
  _Pragma("unroll") for (int i = 0; i < 4; ++i)                                \
    _Pragma("unroll") for (int nf = 0; nf < 4; ++nf)                           \
      acc[(MOFF) + i][nf] =                                                    \
          __builtin_amdgcn_mfma_f32_16x16x32_bf16(aR[i], bR[nf],               \
                                                  acc[(MOFF) + i][nf], 0, 0, 0); \
  __builtin_amdgcn_s_setprio(0);
#define LEADBAR                                                                \
  __builtin_amdgcn_s_barrier();                                                \
  asm volatile("s_waitcnt lgkmcnt(0)" ::: "memory");                           \
  __builtin_amdgcn_sched_barrier(0)
#define TRAILBAR                                                               \
  __builtin_amdgcn_s_barrier();                                                \
  __builtin_amdgcn_sched_barrier(0)

#define GTILE(DD, KT, SON, LAST)                                               \
  {                                                                            \
    bf16x8 aR[4], bk0[4], bk1[4];                                              \
    /* ---- ph0: kk0, m-half0 */                                               \
    RD_A(aR, 0, 0, DD); RD_B(bk0, 1, DD);                                      \
    if (SON) STG(A_, mrow0, (KT) + 1, 0, (DD) ^ 1, 0);                         \
    LEADBAR;                                                                   \
    MFMA16(aR, bk0, 0);                                                        \
    TRAILBAR;                                                                  \
    /* ---- ph1: kk0, m-half1 */                                               \
    RD_A(aR, 1, 0, DD);                                                        \
    if (SON) STG(Bw, n0, (KT) + 1, 0, (DD) ^ 1, 1);                            \
    LEADBAR;                                                                   \
    MFMA16(aR, bk0, 4);                                                        \
    if (LAST) { asm volatile("s_waitcnt vmcnt(0)" ::: "memory"); }             \
    else      { asm volatile("s_waitcnt vmcnt(4)" ::: "memory"); }             \
    __builtin_amdgcn_sched_barrier(0);                                         \
    TRAILBAR;                                                                  \
    /* ---- ph2: kk1, m-half0 */                                               \
    RD_A(aR, 0, 2, DD); RD_B(bk1, 3, DD);                                      \
    if (SON) STG(A_, mrow0, (KT) + 1, 1, (DD) ^ 1, 2);                         \
    LEADBAR;                                                                   \
    MFMA16(aR, bk1, 0);                                                        \
    TRAILBAR;                                                                  \
    /* ---- ph3: kk1, m-half1 */                                               \
    RD_A(aR, 1, 2, DD);                                                        \
    if (SON) STG(Bw, n0, (KT) + 1, 1, (DD) ^ 1, 3);                            \
    LEADBAR;                                                                   \
    MFMA16(aR, bk1, 4);                                                        \
    if (SON) {                                                                 \
      asm volatile("s_waitcnt vmcnt(4)" ::: "memory");                         \
      __builtin_amdgcn_sched_barrier(0);                                       \
    }                                                                          \
    TRAILBAR;                                                                  \
  }

  // prologue: stage tile 0 (u0..u3), drain kk0 (keep kk1's 4 instr in flight)
  STG(A_, mrow0, 0, 0, 0, 0);
  STG(Bw, n0, 0, 0, 0, 1);
  STG(A_, mrow0, 0, 1, 0, 2);
  STG(Bw, n0, 0, 1, 0, 3);
  asm volatile("s_waitcnt vmcnt(4)" ::: "memory");
  __builtin_amdgcn_sched_barrier(0);
  __builtin_amdgcn_s_barrier();
  __builtin_amdgcn_sched_barrier(0);

  for (int kt = 0; kt < ktiles - 1; ++kt) {
    const int D = kt & 1;
    GTILE(D, kt, 1, 0);
  }
  {  // peeled last tile: no stages; final drain at end-ph1
    const int D = (ktiles - 1) & 1;
    GTILE(D, ktiles - 1, 0, 1);
  }
#undef GTILE
#undef STG
#undef RD_A
#undef RD_B
#undef MFMA16
#undef LEADBAR
#undef TRAILBAR

  const float* bp = (sel == 0) ? b0_ : (sel == 1 ? b1_ : b2_);
  void* op = (sel == 0) ? o0 : (sel == 1 ? o1 : o2);
  if (MODE == 0) {
#pragma unroll
    for (int nf = 0; nf < 4; ++nf) {
      int col = n0 + wn * 64 + nf * 16 + c;
      float bv = bp[col];
#pragma unroll
      for (int mf = 0; mf < 8; ++mf) {
        int row = mrow0 + wm * 128 + mf * 16 + g * 4;
#pragma unroll
        for (int r = 0; r < 4; ++r)
          ((u16*)op)[(size_t)(row + r) * cHID + col] = f2b(acc[mf][nf][r] + bv);
      }
    }
  } else {
    float* fp = (float*)op + (size_t)blockIdx.y * cM * cHID;
#pragma unroll
    for (int nf = 0; nf < 4; ++nf) {
      int col = n0 + wn * 64 + nf * 16 + c;
#pragma unroll
      for (int mf = 0; mf < 8; ++mf) {
        int row = mrow0 + wm * 128 + mf * 16 + g * 4;
#pragma unroll
        for (int r = 0; r < 4; ++r)
          fp[(size_t)(row + r) * cHID + col] = acc[mf][nf][r];
      }
    }
  }
}

// ---------------- split-K combine: out = P0 + P1 + bias ----------------
__global__ void combine_bias(const float* __restrict__ P,
                             const float* __restrict__ bias,
                             float* __restrict__ out) {
  int i = blockIdx.x * blockDim.x + threadIdx.x;   // over cM*cHID/4
  float4 a = ((const float4*)P)[i];
  float4 b = ((const float4*)P)[i + (cM * cHID / 4)];
  int col4 = (i & (cHID / 4 - 1)) * 4;
  float4 bb = *reinterpret_cast<const float4*>(bias + col4);
  float4 r;
  r.x = a.x + b.x + bb.x; r.y = a.y + b.y + bb.y;
  r.z = a.z + b.z + bb.z; r.w = a.w + b.w + bb.w;
  ((float4*)out)[i] = r;
}

// ---------------- round-6 128x256 GEMM (fallback path) --------------------
template <int MODE>   // 0: bf16 out, 1: f32 out
__global__ __launch_bounds__(512, 2)
void gemm8(const u16* __restrict__ A,
           const u16* __restrict__ W0, const u16* __restrict__ W1,
           const u16* __restrict__ W2,
           const float* __restrict__ b0, const float* __restrict__ b1,
           const float* __restrict__ b2,
           void* o0, void* o1, void* o2) {
  __shared__ __align__(16) u16 sA[3][128 * 64];
  __shared__ __align__(16) u16 sB[3][256 * 64];
  const int tid = threadIdx.x;
  const int wid = tid >> 6, lane = tid & 63;
  const int c = lane & 15, g = lane >> 4;
  const int wm = wid >> 2, wn = wid & 3;
  const int m0 = blockIdx.x * 128;
  const int gn0 = blockIdx.y * 256;
  const int sel = gn0 >> 12;
  const int n0 = gn0 & 4095;
  const u16* Bw = (sel == 0) ? W0 : (sel == 1 ? W1 : W2);

  f32x4 acc[4][4] = {};
  const int nkt = cHID / 64;

#define STAGE_A(kt, dst)                                                       \
  {                                                                            \
    _Pragma("unroll") for (int l = 0; l < 2; ++l) {                            \
      int chunk = (l * 8 + wid) * 64 + lane;                                   \
      int row = chunk >> 3, kc = (chunk & 7) ^ (row & 7);                      \
      __builtin_amdgcn_global_load_lds(                                        \
          (const void*)(A + (size_t)(m0 + row) * cHID + (kt) * 64 + kc * 8),   \
          (void*)(&sA[dst][(l * 8 + wid) * 512]), 16, 0, 0);                   \
    }                                                                          \
  }
#define STAGE_B(kt, dst)                                                       \
  {                                                                            \
    _Pragma("unroll") for (int l = 0; l < 4; ++l) {                            \
      int chunk = (l * 8 + wid) * 64 + lane;                                   \
      int row = chunk >> 3, kc = (chunk & 7) ^ (row & 7);                      \
      __builtin_amdgcn_global_load_lds(                                        \
          (const void*)(Bw + (size_t)(n0 + row) * cHID + (kt) * 64 + kc * 8),  \
          (void*)(&sB[dst][(l * 8 + wid) * 512]), 16, 0, 0);                   \
    }                                                                          \
  }

  STAGE_A(0, 0); STAGE_B(0, 0);
  STAGE_A(1, 1); STAGE_B(1, 1);
  asm volatile("s_waitcnt vmcnt(6)" ::: "memory");
  __builtin_amdgcn_sched_barrier(0);
  __builtin_amdgcn_s_barrier();
  asm volatile("" ::: "memory");
  __builtin_amdgcn_sched_barrier(0);

  for (int kt = 0; kt < nkt; ++kt) {
    const int bufR = kt % 3;
    const int bufW = (kt + 2) % 3;
    const bool doStage = (kt + 2) < nkt;

    bf16x8 af[4], bw[4];
#pragma unroll
    for (int mf = 0; mf < 4; ++mf) {
      int ra = wm * 64 + mf * 16 + c;
      af[mf] = *reinterpret_cast<const bf16x8*>(
          &sA[bufR][ra * 64 + ((g ^ (ra & 7)) * 8)]);
    }
#pragma unroll
    for (int nf = 0; nf < 4; ++nf) {
      int rb = wn * 64 + nf * 16 + c;
      bw[nf] = *reinterpret_cast<const bf16x8*>(
          &sB[bufR][rb * 64 + ((g ^ (rb & 7)) * 8)]);
    }
    if (doStage) STAGE_A(kt + 2, bufW);
    __builtin_amdgcn_s_setprio(1);
#pragma unroll
    for (int mf = 0; mf < 4; ++mf)
#pragma unroll
      for (int nf = 0; nf < 4; ++nf)
        acc[mf][nf] = __builtin_amdgcn_mfma_f32_16x16x32_bf16(af[mf], bw[nf], acc[mf][nf], 0, 0, 0);
    __builtin_amdgcn_s_setprio(0);

#pragma unroll
    for (int mf = 0; mf < 4; ++mf) {
      int ra = wm * 64 + mf * 16 + c;
      af[mf] = *reinterpret_cast<const bf16x8*>(
          &sA[bufR][ra * 64 + (((4 + g) ^ (ra & 7)) * 8)]);
    }
#pragma unroll
    for (int nf = 0; nf < 4; ++nf) {
      int rb = wn * 64 + nf * 16 + c;
      bw[nf] = *reinterpret_cast<const bf16x8*>(
          &sB[bufR][rb * 64 + (((4 + g) ^ (rb & 7)) * 8)]);
    }
    if (doStage) STAGE_B(kt + 2, bufW);
    __builtin_amdgcn_s_setprio(1);
#pragma unroll
    for (int mf = 0; mf < 4; ++mf)
#pragma unroll
      for (int nf = 0; nf < 4; ++nf)
        acc[mf][nf] = __builtin_amdgcn_mfma_f32_16x16x32_bf16(af[mf], bw[nf], acc[mf][nf], 0, 0, 0);
    __builtin_amdgcn_s_setprio(0);

    if (doStage) {
      asm volatile("s_waitcnt vmcnt(6)" ::: "memory");
    } else {
      asm volatile("s_waitcnt vmcnt(0)" ::: "memory");
    }
    __builtin_amdgcn_sched_barrier(0);
    __builtin_amdgcn_s_barrier();
    asm volatile("" ::: "memory");
    __builtin_amdgcn_sched_barrier(0);
  }
#undef STAGE_A
#undef STAGE_B

  const float* bp = (sel == 0) ? b0 : (sel == 1 ? b1 : b2);
  void* op = (sel == 0) ? o0 : (sel == 1 ? o1 : o2);
#pragma unroll
  for (int nf = 0; nf < 4; ++nf) {
    int col = n0 + wn * 64 + nf * 16 + c;
    float bv = bp[col];
#pragma unroll
    for (int mf = 0; mf < 4; ++mf) {
      int row = m0 + wm * 64 + mf * 16 + g * 4;
#pragma unroll
      for (int r = 0; r < 4; ++r) {
        float v = acc[mf][nf][r] + bv;
        if (MODE == 0)
          ((u16*)op)[(size_t)(row + r) * cHID + col] = f2b(v);
        else
          ((float*)op)[(size_t)(row + r) * cHID + col] = v;
      }
    }
  }
}

// ---------------- flash attention (causal), paired q-tiles, 4 waves -------
__global__ __launch_bounds__(256, 2)
void attn_kernel(const u16* __restrict__ Q, const u16* __restrict__ Kb,
                 const u16* __restrict__ Vt, u16* __restrict__ O) {
  __shared__ __align__(16) char sK[2][16384];  // [64 k][128 d] swizzled
  __shared__ __align__(16) char sV[2][16384];  // [128 d][64 k] swizzled
  __shared__ __align__(16) char sP[8192];      // per-wave [16 q][64 k] swizzled
  const int tid = threadIdx.x, w = tid >> 6, lane = tid & 63;
  const int c = lane & 15, g = lane >> 4;
  const int bh = blockIdx.y;
  const int b = bh >> 5, h = bh & 31;
  const int NT = cS / 64;                       // 16
  const int qtA = blockIdx.x, qtB = NT - 1 - blockIdx.x;
  const float kSc = 0.12751744f;                // log2(e)/sqrt(128)

  bf16x8 qf[2][4];
#pragma unroll
  for (int s = 0; s < 2; ++s) {
    int q0s = (s ? qtA : qtB) * 64;
    size_t qrow = ((size_t)(b * cS + q0s + w * 16 + c) * cNH + h) * cHD;
#pragma unroll
    for (int df = 0; df < 4; ++df)
      qf[s][df] = *reinterpret_cast<const bf16x8*>(Q + qrow + df * 32 + g * 8);
  }

  f32x4 o[2][8] = {};
  float mx[2][4], ls[2][4];
#pragma unroll
  for (int s = 0; s < 2; ++s)
#pragma unroll
    for (int r = 0; r < 4; ++r) { mx[s][r] = -1e30f; ls[s][r] = 0.f; }

  uint4 kv[4], vv[4];
#define LOADT(t)                                                               \
  {                                                                            \
    _Pragma("unroll") for (int i = 0; i < 4; ++i) {                            \
      int cidx = i * 256 + tid;                                                \
      { int row = cidx >> 4, ch = cidx & 15;                                   \
        kv[i] = *reinterpret_cast<const uint4*>(                               \
            Kb + ((size_t)(b * cS + (t) * 64 + row) * cNH + h) * cHD + ch * 8); } \
      { int row = cidx >> 3, ch = cidx & 7;                                    \
        vv[i] = *reinterpret_cast<const uint4*>(                               \
            Vt + ((size_t)bh * cHD + row) * cS + (t) * 64 + ch * 8); }         \
    }                                                                          \
  }
#define WRITET(buf)                                                            \
  {                                                                            \
    _Pragma("unroll") for (int i = 0; i < 4; ++i) {                            \
      int cidx = i * 256 + tid;                                                \
      { int row = cidx >> 4, ch = cidx & 15;                                   \
        *reinterpret_cast<uint4*>(sK[buf] + row * 256 + ((ch ^ (row & 7)) * 16)) = kv[i]; } \
      { int row = cidx >> 3, ch = cidx & 7;                                    \
        *reinterpret_cast<uint4*>(sV[buf] + row * 128 + ((ch ^ (row & 7)) * 16)) = vv[i]; } \
    }                                                                          \
  }

  LOADT(0);
  WRITET(0);
  int cur = 0;

  for (int t = 0; t <= qtB; ++t) {
    __syncthreads();
    if (t < qtB) LOADT(t + 1);

#pragma unroll
    for (int s = 0; s < 2; ++s) {
      const int qt_s = s ? qtA : qtB;
      if (t > qt_s) continue;
      const int q0_s = qt_s * 64;

      f32x4 sc[4] = {};
#pragma unroll
      for (int df = 0; df < 4; ++df) {
        bf16x8 kb[4];
#pragma unroll
        for (int cf = 0; cf < 4; ++cf) {
          int kr = cf * 16 + c;
          kb[cf] = *reinterpret_cast<const bf16x8*>(sK[cur] + kr * 256 + (((df * 4 + g) ^ (kr & 7)) * 16));
        }
#pragma unroll
        for (int cf = 0; cf < 4; ++cf)
          sc[cf] = __builtin_amdgcn_mfma_f32_16x16x32_bf16(qf[s][df], kb[cf], sc[cf], 0, 0, 0);
      }

      if (t == qt_s) {
#pragma unroll
        for (int cf = 0; cf < 4; ++cf) {
          int kg = t * 64 + cf * 16 + c;
#pragma unroll
          for (int r = 0; r < 4; ++r) {
            int qg = q0_s + w * 16 + g * 4 + r;
            if (kg > qg) sc[cf][r] = -1e30f;
          }
        }
      }

      float alpha[4];
#pragma unroll
      for (int r = 0; r < 4; ++r) {
        float v = fmaxf(fmaxf(sc[0][r], sc[1][r]), fmaxf(sc[2][r], sc[3][r]));
        v = fmaxf(v, __shfl_xor(v, 1));
        v = fmaxf(v, __shfl_xor(v, 2));
        v = fmaxf(v, __shfl_xor(v, 4));
        v = fmaxf(v, __shfl_xor(v, 8));
        float mn = fmaxf(mx[s][r], v);
        alpha[r] = exp2f((mx[s][r] - mn) * kSc);
        mx[s][r] = mn;
      }
      float rs[4] = {0.f, 0.f, 0.f, 0.f};
#pragma unroll
      for (int cf = 0; cf < 4; ++cf)
#pragma unroll
        for (int r = 0; r < 4; ++r) {
          float p = exp2f((sc[cf][r] - mx[s][r]) * kSc);
          sc[cf][r] = p;
          rs[r] += p;
        }
#pragma unroll
      for (int r = 0; r < 4; ++r) {
        float v = rs[r];
        v += __shfl_xor(v, 1); v += __shfl_xor(v, 2);
        v += __shfl_xor(v, 4); v += __shfl_xor(v, 8);
        ls[s][r] = ls[s][r] * alpha[r] + v;
      }
#pragma unroll
      for (int nf = 0; nf < 8; ++nf)
#pragma unroll
        for (int r = 0; r < 4; ++r)
          o[s][nf][r] *= alpha[r];

      char* myP = sP + w * 2048;
#pragma unroll
      for (int cf = 0; cf < 4; ++cf) {
        int kcol = cf * 16 + c;
        int chunk = kcol >> 3, within = kcol & 7;
#pragma unroll
        for (int r = 0; r < 4; ++r) {
          int qr = g * 4 + r;
          *reinterpret_cast<u16*>(myP + qr * 128 + ((chunk ^ (qr & 7)) * 16) + within * 2) =
              f2b(sc[cf][r]);
        }
      }
      bf16x8 pa[2];
#pragma unroll
      for (int kf = 0; kf < 2; ++kf)
        pa[kf] = *reinterpret_cast<const bf16x8*>(myP + c * 128 + (((kf * 4 + g) ^ (c & 7)) * 16));

#pragma unroll
      for (int kf = 0; kf < 2; ++kf) {
#pragma unroll
        for (int nf = 0; nf < 8; ++nf) {
          int dr = nf * 16 + c;
          bf16x8 vb = *reinterpret_cast<const bf16x8*>(sV[cur] + dr * 128 + (((kf * 4 + g) ^ (dr & 7)) * 16));
          o[s][nf] = __builtin_amdgcn_mfma_f32_16x16x32_bf16(pa[kf], vb, o[s][nf], 0, 0, 0);
        }
      }
    }

    if (t < qtB) { WRITET(cur ^ 1); cur ^= 1; }
  }

  __syncthreads();
#pragma unroll
  for (int s = 0; s < 2; ++s) {
#pragma unroll
    for (int nf = 0; nf < 8; ++nf) {
#pragma unroll
      for (int r = 0; r < 4; ++r) {
        float v = o[s][nf][r] / ls[s][r];
        int qr = w * 16 + g * 4 + r;
        *reinterpret_cast<u16*>(sK[s] + qr * 256 + (nf * 16 + c) * 2) = f2b(v);
      }
    }
  }
  __syncthreads();
#pragma unroll
  for (int s = 0; s < 2; ++s) {
    int q0_s = (s ? qtA : qtB) * 64;
#pragma unroll
    for (int i = 0; i < 4; ++i) {
      int cidx = i * 256 + tid;
      int row = cidx >> 4, ch = cidx & 15;
      uint4 v = *reinterpret_cast<const uint4*>(sK[s] + row * 256 + ch * 16);
      *reinterpret_cast<uint4*>(O + ((size_t)(b * cS + q0_s + row) * cNH + h) * cHD + ch * 8) = v;
    }
  }
#undef LOADT
#undef WRITET
}

// ---------------- host ----------------
extern "C" void kernel_launch(void* const* d_in, const int* in_sizes, int n_in,
                              void* d_out, int out_size, void* d_ws, size_t ws_size,
                              hipStream_t stream) {
  const float* x  = (const float*)d_in[0];
  const float* Wq = (const float*)d_in[1];
  const float* bq = (const float*)d_in[2];
  const float* Wk = (const float*)d_in[3];
  const float* bk = (const float*)d_in[4];
  const float* Wv = (const float*)d_in[5];
  const float* bv = (const float*)d_in[6];
  const float* Wo = (const float*)d_in[7];
  const float* bo = (const float*)d_in[8];
  const int*  pos = (const int*)d_in[9];
  float* out = (float*)d_out;

  char* ws = (char*)d_ws;
  const size_t MB = 1u << 20;
  const int W8 = (cHID * cHID) / 8;     // 2,097,152
  const int X8 = (cM * cHID) / 8;       // 1,048,576
  const int R8 = cB * cS * cNH * (cHD / 8);

  if (ws_size >= 168 * MB) {
    // -------- fused path (168 MiB) --------
    u16* xb  = (u16*)(ws);                 // 0-16
    u16* Qb  = (u16*)(ws + 16 * MB);       // 16-32
    u16* Kb  = (u16*)(ws + 32 * MB);       // 32-48
    u16* Vb  = (u16*)(ws + 48 * MB);       // 48-64
    float* cosT = (float*)(ws + 64 * MB);  // 64-65
    float* sinT = cosT + cB * cS * 64;
    u16* WbQ = (u16*)(ws + 72 * MB);       // 72-104
    u16* WbK = (u16*)(ws + 104 * MB);      // 104-136
    u16* WbV = (u16*)(ws + 136 * MB);      // 136-168
    u16* Vt  = WbQ;                        // weights dead after QKV GEMM
    u16* Ab  = WbK;
    u16* WbO = WbV;
    float* P01 = (float*)(ws);             // 0-67: split-K partials (xb..cosT dead)

    cvt_bf16<<<X8 / 256, 256, 0, stream>>>(x, xb, X8);
    cvt_bf16<<<W8 / 256, 256, 0, stream>>>(Wq, WbQ, W8);
    cvt_bf16<<<W8 / 256, 256, 0, stream>>>(Wk, WbK, W8);
    cvt_bf16<<<W8 / 256, 256, 0, stream>>>(Wv, WbV, W8);
    rope_table_k<<<(cB * cS * 64) / 256, 256, 0, stream>>>(pos, cosT, sinT);

    gemm256<0, 6><<<dim3(384), 512, 0, stream>>>(
        xb, WbQ, WbK, WbV, bq, bk, bv, Qb, Kb, Vb, 64);

    rope_apply<<<(2 * R8) / 256, 256, 0, stream>>>(Qb, Kb, cosT, sinT);
    transpose_v<<<dim3(cS / 32, cHD / 32, cB * cNH), 256, 0, stream>>>(Vb, Vt);
    attn_kernel<<<dim3(cS / 128, cB * cNH), 256, 0, stream>>>(Qb, Kb, Vt, Ab);

    cvt_bf16<<<W8 / 256, 256, 0, stream>>>(Wo, WbO, W8);
    gemm256<2, 2><<<dim3(128, 2), 512, 0, stream>>>(
        Ab, WbO, WbO, WbO, nullptr, nullptr, nullptr, P01, P01, P01, 32);
    combine_bias<<<(cM * cHID / 4) / 256, 256, 0, stream>>>(P01, bo, out);
  } else {
    // -------- fallback serial path (97 MiB, round-6-proven) --------
    u16* xb = (u16*)(ws);                 // 0-16, later Vt
    u16* Wb = (u16*)(ws + 16 * MB);       // 16-48
    u16* Qb = (u16*)(ws + 48 * MB);       // 48-64
    u16* Kb = (u16*)(ws + 64 * MB);       // 64-80
    u16* Vb = (u16*)(ws + 80 * MB);       // 80-96, later attn out
    u16* Vt = xb;
    u16* Ab = Vb;
    float* cosT = (float*)(ws + 96 * MB);
    float* sinT = cosT + cB * cS * 64;

    cvt_bf16<<<X8 / 256, 256, 0, stream>>>(x, xb, X8);
    cvt_bf16<<<W8 / 256, 256, 0, stream>>>(Wq, Wb, W8);
    gemm8<0><<<dim3(16, 16), 512, 0, stream>>>(
        xb, Wb, Wb, Wb, bq, bq, bq, Qb, Qb, Qb);
    cvt_bf16<<<W8 / 256, 256, 0, stream>>>(Wk, Wb, W8);
    gemm8<0><<<dim3(16, 16), 512, 0, stream>>>(
        xb, Wb, Wb, Wb, bk, bk, bk, Kb, Kb, Kb);
    cvt_bf16<<<W8 / 256, 256, 0, stream>>>(Wv, Wb, W8);
    gemm8<0><<<dim3(16, 16), 512, 0, stream>>>(
        xb, Wb, Wb, Wb, bv, bv, bv, Vb, Vb, Vb);

    rope_table_k<<<(cB * cS * 64) / 256, 256, 0, stream>>>(pos, cosT, sinT);
    rope_apply<<<(2 * R8) / 256, 256, 0, stream>>>(Qb, Kb, cosT, sinT);
    transpose_v<<<dim3(cS / 32, cHD / 32, cB * cNH), 256, 0, stream>>>(Vb, Vt);
    attn_kernel<<<dim3(cS / 128, cB * cNH), 256, 0, stream>>>(Qb, Kb, Vt, Ab);

    cvt_bf16<<<W8 / 256, 256, 0, stream>>>(Wo, Wb, W8);
    gemm8<1><<<dim3(16, 16), 512, 0, stream>>>(
        Ab, Wb, Wb, Wb, bo, bo, bo, out, out, out);
  }
}

// Round 8
// 468.105 us; speedup vs baseline: 1.0758x; 1.0758x over previous
//
#include <hip/hip_runtime.h>
#include <hip/hip_bf16.h>
#include <cmath>

// ---- problem constants ----
constexpr int cB  = 2;
constexpr int cS  = 1024;
constexpr int cNH = 32;
constexpr int cHD = 128;
constexpr int cHID = 4096;
constexpr int cM  = cB * cS;        // 2048 rows

typedef unsigned short u16;
typedef __bf16 bf16x8 __attribute__((ext_vector_type(8)));
typedef float  f32x4  __attribute__((ext_vector_type(4)));

__device__ __forceinline__ u16 f2b(float f) { return __builtin_bit_cast(u16, (__bf16)f); }

// ---------------- f32 -> bf16, 8 elems/thread ----------------
__global__ void cvt_bf16(const float* __restrict__ in, u16* __restrict__ out, int n8) {
  int i = blockIdx.x * blockDim.x + threadIdx.x;
  if (i >= n8) return;
  const float4* in4 = (const float4*)in;
  float4 a = in4[2 * i], b = in4[2 * i + 1];
  union { u16 u[8]; uint4 v; } r;
  r.u[0] = f2b(a.x); r.u[1] = f2b(a.y); r.u[2] = f2b(a.z); r.u[3] = f2b(a.w);
  r.u[4] = f2b(b.x); r.u[5] = f2b(b.y); r.u[6] = f2b(b.z); r.u[7] = f2b(b.w);
  ((uint4*)out)[i] = r.v;
}

// ---------------- RoPE cos/sin table: [B*S][64] ----------------
__global__ void rope_table_k(const int* __restrict__ pos,
                             float* __restrict__ cosT, float* __restrict__ sinT) {
  int idx = blockIdx.x * blockDim.x + threadIdx.x;   // < B*S*64
  int i = idx & 63, bs = idx >> 6;
  float p = (float)pos[bs];
  float freq = exp2f(-(float)i * (13.287712379549449f / 64.0f));
  float a = p * freq;
  float s, c;
  sincosf(a, &s, &c);
  cosT[idx] = c; sinT[idx] = s;
}

// ---------------- RoPE in-place on Q and K (bf16), interleaved pairs ------
__global__ void rope_apply(u16* __restrict__ Q, u16* __restrict__ Kb,
                           const float* __restrict__ cosT, const float* __restrict__ sinT) {
  int idx = blockIdx.x * blockDim.x + threadIdx.x;
  const int nPer = cB * cS * cNH * (cHD / 8);        // 1,048,576
  u16* P = (idx < nPer) ? Q : Kb;
  int t = (idx < nPer) ? idx : idx - nPer;
  int d8 = t & 15;
  int h  = (t >> 4) & 31;
  int bs = t >> 9;
  size_t base = ((size_t)bs * cNH + h) * cHD + d8 * 8;
  uint4 v = *reinterpret_cast<uint4*>(P + base);
  u16* u = reinterpret_cast<u16*>(&v);
  int pb = bs * 64 + d8 * 4;
  float4 cs = *reinterpret_cast<const float4*>(cosT + pb);
  float4 sn = *reinterpret_cast<const float4*>(sinT + pb);
  float co[4] = {cs.x, cs.y, cs.z, cs.w};
  float si[4] = {sn.x, sn.y, sn.z, sn.w};
#pragma unroll
  for (int p = 0; p < 4; ++p) {
    float e = (float)__builtin_bit_cast(__bf16, u[2 * p]);
    float o = (float)__builtin_bit_cast(__bf16, u[2 * p + 1]);
    float e2 = e * co[p] - o * si[p];
    float o2 = o * co[p] + e * si[p];
    u[2 * p]     = f2b(e2);
    u[2 * p + 1] = f2b(o2);
  }
  *reinterpret_cast<uint4*>(P + base) = v;
}

// ---------------- V [B,S,NH,HD] -> Vt [B*NH, HD, S] ----------------
__global__ void transpose_v(const u16* __restrict__ V, u16* __restrict__ Vt) {
  __shared__ u16 tile[32][33];
  int bh = blockIdx.z;
  int b = bh >> 5, h = bh & 31;
  int s0 = blockIdx.x * 32, d0 = blockIdx.y * 32;
  int tx = threadIdx.x & 31, ty0 = threadIdx.x >> 5;
#pragma unroll
  for (int i = 0; i < 4; ++i) {
    int r = ty0 + i * 8;
    tile[r][tx] = V[((size_t)(b * cS + s0 + r) * cNH + h) * cHD + d0 + tx];
  }
  __syncthreads();
#pragma unroll
  for (int i = 0; i < 4; ++i) {
    int r = ty0 + i * 8;
    Vt[((size_t)bh * cHD + d0 + r) * cS + s0 + tx] = tile[tx][r];
  }
}

// ---------------- pipelined GEMM: C[M,Ntot] = A @ [W0;W1;W2]^T + bias -----
// Round-6-proven: 128x256 tile, BK=64, 512 thr/8 waves, depth-2 prefetch,
// 3 LDS buffers, ONE barrier per K-tile, counted vmcnt(6), T2 swizzle both
// sides (bank conflicts = 0), setprio-wrapped MFMA clusters.
// Grid x=m (consecutive blocks share weight panel), y=n. 768/256 blocks =
// exact generations at 1 block/CU.
template <int MODE>   // 0: bf16 out, 1: f32 out
__global__ __launch_bounds__(512, 2)
void gemm8(const u16* __restrict__ A,
           const u16* __restrict__ W0, const u16* __restrict__ W1,
           const u16* __restrict__ W2,
           const float* __restrict__ b0, const float* __restrict__ b1,
           const float* __restrict__ b2,
           void* o0, void* o1, void* o2) {
  __shared__ __align__(16) u16 sA[3][128 * 64];
  __shared__ __align__(16) u16 sB[3][256 * 64];
  const int tid = threadIdx.x;
  const int wid = tid >> 6, lane = tid & 63;
  const int c = lane & 15, g = lane >> 4;
  const int wm = wid >> 2, wn = wid & 3;
  const int m0 = blockIdx.x * 128;
  const int gn0 = blockIdx.y * 256;
  const int sel = gn0 >> 12;
  const int n0 = gn0 & 4095;
  const u16* Bw = (sel == 0) ? W0 : (sel == 1 ? W1 : W2);

  f32x4 acc[4][4] = {};
  const int nkt = cHID / 64;

#define STAGE_A(kt, dst)                                                       \
  {                                                                            \
    _Pragma("unroll") for (int l = 0; l < 2; ++l) {                            \
      int chunk = (l * 8 + wid) * 64 + lane;                                   \
      int row = chunk >> 3, kc = (chunk & 7) ^ (row & 7);                      \
      __builtin_amdgcn_global_load_lds(                                        \
          (const void*)(A + (size_t)(m0 + row) * cHID + (kt) * 64 + kc * 8),   \
          (void*)(&sA[dst][(l * 8 + wid) * 512]), 16, 0, 0);                   \
    }                                                                          \
  }
#define STAGE_B(kt, dst)                                                       \
  {                                                                            \
    _Pragma("unroll") for (int l = 0; l < 4; ++l) {                            \
      int chunk = (l * 8 + wid) * 64 + lane;                                   \
      int row = chunk >> 3, kc = (chunk & 7) ^ (row & 7);                      \
      __builtin_amdgcn_global_load_lds(                                        \
          (const void*)(Bw + (size_t)(n0 + row) * cHID + (kt) * 64 + kc * 8),  \
          (void*)(&sB[dst][(l * 8 + wid) * 512]), 16, 0, 0);                   \
    }                                                                          \
  }

  STAGE_A(0, 0); STAGE_B(0, 0);
  STAGE_A(1, 1); STAGE_B(1, 1);
  asm volatile("s_waitcnt vmcnt(6)" ::: "memory");
  __builtin_amdgcn_sched_barrier(0);
  __builtin_amdgcn_s_barrier();
  asm volatile("" ::: "memory");
  __builtin_amdgcn_sched_barrier(0);

  for (int kt = 0; kt < nkt; ++kt) {
    const int bufR = kt % 3;
    const int bufW = (kt + 2) % 3;
    const bool doStage = (kt + 2) < nkt;

    bf16x8 af[4], bw[4];
#pragma unroll
    for (int mf = 0; mf < 4; ++mf) {
      int ra = wm * 64 + mf * 16 + c;
      af[mf] = *reinterpret_cast<const bf16x8*>(
          &sA[bufR][ra * 64 + ((g ^ (ra & 7)) * 8)]);
    }
#pragma unroll
    for (int nf = 0; nf < 4; ++nf) {
      int rb = wn * 64 + nf * 16 + c;
      bw[nf] = *reinterpret_cast<const bf16x8*>(
          &sB[bufR][rb * 64 + ((g ^ (rb & 7)) * 8)]);
    }
    if (doStage) STAGE_A(kt + 2, bufW);
    __builtin_amdgcn_s_setprio(1);
#pragma unroll
    for (int mf = 0; mf < 4; ++mf)
#pragma unroll
      for (int nf = 0; nf < 4; ++nf)
        acc[mf][nf] = __builtin_amdgcn_mfma_f32_16x16x32_bf16(af[mf], bw[nf], acc[mf][nf], 0, 0, 0);
    __builtin_amdgcn_s_setprio(0);

#pragma unroll
    for (int mf = 0; mf < 4; ++mf) {
      int ra = wm * 64 + mf * 16 + c;
      af[mf] = *reinterpret_cast<const bf16x8*>(
          &sA[bufR][ra * 64 + (((4 + g) ^ (ra & 7)) * 8)]);
    }
#pragma unroll
    for (int nf = 0; nf < 4; ++nf) {
      int rb = wn * 64 + nf * 16 + c;
      bw[nf] = *reinterpret_cast<const bf16x8*>(
          &sB[bufR][rb * 64 + (((4 + g) ^ (rb & 7)) * 8)]);
    }
    if (doStage) STAGE_B(kt + 2, bufW);
    __builtin_amdgcn_s_setprio(1);
#pragma unroll
    for (int mf = 0; mf < 4; ++mf)
#pragma unroll
      for (int nf = 0; nf < 4; ++nf)
        acc[mf][nf] = __builtin_amdgcn_mfma_f32_16x16x32_bf16(af[mf], bw[nf], acc[mf][nf], 0, 0, 0);
    __builtin_amdgcn_s_setprio(0);

    if (doStage) {
      asm volatile("s_waitcnt vmcnt(6)" ::: "memory");
    } else {
      asm volatile("s_waitcnt vmcnt(0)" ::: "memory");
    }
    __builtin_amdgcn_sched_barrier(0);
    __builtin_amdgcn_s_barrier();
    asm volatile("" ::: "memory");
    __builtin_amdgcn_sched_barrier(0);
  }
#undef STAGE_A
#undef STAGE_B

  const float* bp = (sel == 0) ? b0 : (sel == 1 ? b1 : b2);
  void* op = (sel == 0) ? o0 : (sel == 1 ? o1 : o2);
#pragma unroll
  for (int nf = 0; nf < 4; ++nf) {
    int col = n0 + wn * 64 + nf * 16 + c;
    float bv = bp[col];
#pragma unroll
    for (int mf = 0; mf < 4; ++mf) {
      int row = m0 + wm * 64 + mf * 16 + g * 4;
#pragma unroll
      for (int r = 0; r < 4; ++r) {
        float v = acc[mf][nf][r] + bv;
        if (MODE == 0)
          ((u16*)op)[(size_t)(row + r) * cHID + col] = f2b(v);
        else
          ((float*)op)[(size_t)(row + r) * cHID + col] = v;
      }
    }
  }
}

// ---------------- flash attention (causal), paired q-tiles, 4 waves -------
// NEW (m169 / Common-mistake #7): V is NOT LDS-staged — K/V are L2/L3
// resident at S=1024 (256 KB/head), so PV reads V fragments straight from
// global Vt [bh][d][s], batched 8-in-flight per kf-half to cover L2 latency.
// K stays double-buffered in LDS (swizzled). LDS 72 KB -> 40 KB.
__global__ __launch_bounds__(256, 2)
void attn_kernel(const u16* __restrict__ Q, const u16* __restrict__ Kb,
                 const u16* __restrict__ Vt, u16* __restrict__ O) {
  __shared__ __align__(16) char sK[2][16384];  // [64 k][128 d] swizzled
  __shared__ __align__(16) char sP[8192];      // per-wave [16 q][64 k] swizzled
  const int tid = threadIdx.x, w = tid >> 6, lane = tid & 63;
  const int c = lane & 15, g = lane >> 4;
  const int bh = blockIdx.y;
  const int b = bh >> 5, h = bh & 31;
  const int NT = cS / 64;                       // 16
  const int qtA = blockIdx.x, qtB = NT - 1 - blockIdx.x;
  const float kSc = 0.12751744f;                // log2(e)/sqrt(128)
  const u16* Vg = Vt + (size_t)bh * (cHD * cS); // [128 d][1024 s]

  bf16x8 qf[2][4];
#pragma unroll
  for (int s = 0; s < 2; ++s) {
    int q0s = (s ? qtA : qtB) * 64;
    size_t qrow = ((size_t)(b * cS + q0s + w * 16 + c) * cNH + h) * cHD;
#pragma unroll
    for (int df = 0; df < 4; ++df)
      qf[s][df] = *reinterpret_cast<const bf16x8*>(Q + qrow + df * 32 + g * 8);
  }

  f32x4 o[2][8] = {};
  float mx[2][4], ls[2][4];
#pragma unroll
  for (int s = 0; s < 2; ++s)
#pragma unroll
    for (int r = 0; r < 4; ++r) { mx[s][r] = -1e30f; ls[s][r] = 0.f; }

  uint4 kv[4];
#define LOADT(t)                                                               \
  {                                                                            \
    _Pragma("unroll") for (int i = 0; i < 4; ++i) {                            \
      int cidx = i * 256 + tid;                                                \
      int row = cidx >> 4, ch = cidx & 15;                                     \
      kv[i] = *reinterpret_cast<const uint4*>(                                 \
          Kb + ((size_t)(b * cS + (t) * 64 + row) * cNH + h) * cHD + ch * 8);  \
    }                                                                          \
  }
#define WRITET(buf)                                                            \
  {                                                                            \
    _Pragma("unroll") for (int i = 0; i < 4; ++i) {                            \
      int cidx = i * 256 + tid;                                                \
      int row = cidx >> 4, ch = cidx & 15;                                     \
      *reinterpret_cast<uint4*>(sK[buf] + row * 256 + ((ch ^ (row & 7)) * 16)) = kv[i]; \
    }                                                                          \
  }

  LOADT(0);
  WRITET(0);
  int cur = 0;

  for (int t = 0; t <= qtB; ++t) {
    __syncthreads();
    if (t < qtB) LOADT(t + 1);

#pragma unroll
    for (int s = 0; s < 2; ++s) {
      const int qt_s = s ? qtA : qtB;
      if (t > qt_s) continue;
      const int q0_s = qt_s * 64;

      f32x4 sc[4] = {};
#pragma unroll
      for (int df = 0; df < 4; ++df) {
        bf16x8 kb[4];
#pragma unroll
        for (int cf = 0; cf < 4; ++cf) {
          int kr = cf * 16 + c;
          kb[cf] = *reinterpret_cast<const bf16x8*>(sK[cur] + kr * 256 + (((df * 4 + g) ^ (kr & 7)) * 16));
        }
#pragma unroll
        for (int cf = 0; cf < 4; ++cf)
          sc[cf] = __builtin_amdgcn_mfma_f32_16x16x32_bf16(qf[s][df], kb[cf], sc[cf], 0, 0, 0);
      }

      if (t == qt_s) {
#pragma unroll
        for (int cf = 0; cf < 4; ++cf) {
          int kg = t * 64 + cf * 16 + c;
#pragma unroll
          for (int r = 0; r < 4; ++r) {
            int qg = q0_s + w * 16 + g * 4 + r;
            if (kg > qg) sc[cf][r] = -1e30f;
          }
        }
      }

      float alpha[4];
#pragma unroll
      for (int r = 0; r < 4; ++r) {
        float v = fmaxf(fmaxf(sc[0][r], sc[1][r]), fmaxf(sc[2][r], sc[3][r]));
        v = fmaxf(v, __shfl_xor(v, 1));
        v = fmaxf(v, __shfl_xor(v, 2));
        v = fmaxf(v, __shfl_xor(v, 4));
        v = fmaxf(v, __shfl_xor(v, 8));
        float mn = fmaxf(mx[s][r], v);
        alpha[r] = exp2f((mx[s][r] - mn) * kSc);
        mx[s][r] = mn;
      }
      float rs[4] = {0.f, 0.f, 0.f, 0.f};
#pragma unroll
      for (int cf = 0; cf < 4; ++cf)
#pragma unroll
        for (int r = 0; r < 4; ++r) {
          float p = exp2f((sc[cf][r] - mx[s][r]) * kSc);
          sc[cf][r] = p;
          rs[r] += p;
        }
#pragma unroll
      for (int r = 0; r < 4; ++r) {
        float v = rs[r];
        v += __shfl_xor(v, 1); v += __shfl_xor(v, 2);
        v += __shfl_xor(v, 4); v += __shfl_xor(v, 8);
        ls[s][r] = ls[s][r] * alpha[r] + v;
      }
#pragma unroll
      for (int nf = 0; nf < 8; ++nf)
#pragma unroll
        for (int r = 0; r < 4; ++r)
          o[s][nf][r] *= alpha[r];

      // ---- P (C layout) -> per-wave LDS (bf16, swizzled) for A-operand
      char* myP = sP + w * 2048;
#pragma unroll
      for (int cf = 0; cf < 4; ++cf) {
        int kcol = cf * 16 + c;
        int chunk = kcol >> 3, within = kcol & 7;
#pragma unroll
        for (int r = 0; r < 4; ++r) {
          int qr = g * 4 + r;
          *reinterpret_cast<u16*>(myP + qr * 128 + ((chunk ^ (qr & 7)) * 16) + within * 2) =
              f2b(sc[cf][r]);
        }
      }
      bf16x8 pa[2];
#pragma unroll
      for (int kf = 0; kf < 2; ++kf)
        pa[kf] = *reinterpret_cast<const bf16x8*>(myP + c * 128 + (((kf * 4 + g) ^ (c & 7)) * 16));

      // ---- PV: V fragments direct from global (L2-hot), 8 in flight
#pragma unroll
      for (int kf = 0; kf < 2; ++kf) {
        bf16x8 vb[8];
#pragma unroll
        for (int nf = 0; nf < 8; ++nf)
          vb[nf] = *reinterpret_cast<const bf16x8*>(
              Vg + (size_t)(nf * 16 + c) * cS + t * 64 + (kf * 4 + g) * 8);
#pragma unroll
        for (int nf = 0; nf < 8; ++nf)
          o[s][nf] = __builtin_amdgcn_mfma_f32_16x16x32_bf16(pa[kf], vb[nf], o[s][nf], 0, 0, 0);
      }
    }

    if (t < qtB) { WRITET(cur ^ 1); cur ^= 1; }
  }

  __syncthreads();
#pragma unroll
  for (int s = 0; s < 2; ++s) {
#pragma unroll
    for (int nf = 0; nf < 8; ++nf) {
#pragma unroll
      for (int r = 0; r < 4; ++r) {
        float v = o[s][nf][r] / ls[s][r];
        int qr = w * 16 + g * 4 + r;
        *reinterpret_cast<u16*>(sK[s] + qr * 256 + (nf * 16 + c) * 2) = f2b(v);
      }
    }
  }
  __syncthreads();
#pragma unroll
  for (int s = 0; s < 2; ++s) {
    int q0_s = (s ? qtA : qtB) * 64;
#pragma unroll
    for (int i = 0; i < 4; ++i) {
      int cidx = i * 256 + tid;
      int row = cidx >> 4, ch = cidx & 15;
      uint4 v = *reinterpret_cast<const uint4*>(sK[s] + row * 256 + ch * 16);
      *reinterpret_cast<uint4*>(O + ((size_t)(b * cS + q0_s + row) * cNH + h) * cHD + ch * 8) = v;
    }
  }
#undef LOADT
#undef WRITET
}

// ---------------- host ----------------
extern "C" void kernel_launch(void* const* d_in, const int* in_sizes, int n_in,
                              void* d_out, int out_size, void* d_ws, size_t ws_size,
                              hipStream_t stream) {
  const float* x  = (const float*)d_in[0];
  const float* Wq = (const float*)d_in[1];
  const float* bq = (const float*)d_in[2];
  const float* Wk = (const float*)d_in[3];
  const float* bk = (const float*)d_in[4];
  const float* Wv = (const float*)d_in[5];
  const float* bv = (const float*)d_in[6];
  const float* Wo = (const float*)d_in[7];
  const float* bo = (const float*)d_in[8];
  const int*  pos = (const int*)d_in[9];
  float* out = (float*)d_out;

  char* ws = (char*)d_ws;
  const size_t MB = 1u << 20;
  const int W8 = (cHID * cHID) / 8;     // 2,097,152
  const int X8 = (cM * cHID) / 8;       // 1,048,576
  const int R8 = cB * cS * cNH * (cHD / 8);

  if (ws_size >= 168 * MB) {
    // -------- fused path (168 MiB) --------
    u16* xb  = (u16*)(ws);                 // 0-16
    u16* Qb  = (u16*)(ws + 16 * MB);       // 16-32
    u16* Kb  = (u16*)(ws + 32 * MB);       // 32-48
    u16* Vb  = (u16*)(ws + 48 * MB);       // 48-64
    float* cosT = (float*)(ws + 64 * MB);  // 64-65
    float* sinT = cosT + cB * cS * 64;
    u16* WbQ = (u16*)(ws + 72 * MB);       // 72-104
    u16* WbK = (u16*)(ws + 104 * MB);      // 104-136
    u16* WbV = (u16*)(ws + 136 * MB);      // 136-168
    u16* Vt  = WbQ;                        // weights dead after QKV GEMM
    u16* Ab  = WbK;
    u16* WbO = WbV;

    cvt_bf16<<<X8 / 256, 256, 0, stream>>>(x, xb, X8);
    cvt_bf16<<<W8 / 256, 256, 0, stream>>>(Wq, WbQ, W8);
    cvt_bf16<<<W8 / 256, 256, 0, stream>>>(Wk, WbK, W8);
    cvt_bf16<<<W8 / 256, 256, 0, stream>>>(Wv, WbV, W8);
    rope_table_k<<<(cB * cS * 64) / 256, 256, 0, stream>>>(pos, cosT, sinT);

    gemm8<0><<<dim3(16, 48), 512, 0, stream>>>(
        xb, WbQ, WbK, WbV, bq, bk, bv, Qb, Kb, Vb);

    rope_apply<<<(2 * R8) / 256, 256, 0, stream>>>(Qb, Kb, cosT, sinT);
    transpose_v<<<dim3(cS / 32, cHD / 32, cB * cNH), 256, 0, stream>>>(Vb, Vt);
    attn_kernel<<<dim3(cS / 128, cB * cNH), 256, 0, stream>>>(Qb, Kb, Vt, Ab);

    cvt_bf16<<<W8 / 256, 256, 0, stream>>>(Wo, WbO, W8);
    gemm8<1><<<dim3(16, 16), 512, 0, stream>>>(
        Ab, WbO, WbO, WbO, bo, bo, bo, out, out, out);
  } else {
    // -------- fallback serial path (97 MiB) --------
    u16* xb = (u16*)(ws);                 // 0-16, later Vt
    u16* Wb = (u16*)(ws + 16 * MB);       // 16-48
    u16* Qb = (u16*)(ws + 48 * MB);       // 48-64
    u16* Kb = (u16*)(ws + 64 * MB);       // 64-80
    u16* Vb = (u16*)(ws + 80 * MB);       // 80-96, later attn out
    u16* Vt = xb;
    u16* Ab = Vb;
    float* cosT = (float*)(ws + 96 * MB);
    float* sinT = cosT + cB * cS * 64;

    cvt_bf16<<<X8 / 256, 256, 0, stream>>>(x, xb, X8);
    cvt_bf16<<<W8 / 256, 256, 0, stream>>>(Wq, Wb, W8);
    gemm8<0><<<dim3(16, 16), 512, 0, stream>>>(
        xb, Wb, Wb, Wb, bq, bq, bq, Qb, Qb, Qb);
    cvt_bf16<<<W8 / 256, 256, 0, stream>>>(Wk, Wb, W8);
    gemm8<0><<<dim3(16, 16), 512, 0, stream>>>(
        xb, Wb, Wb, Wb, bk, bk, bk, Kb, Kb, Kb);
    cvt_bf16<<<W8 / 256, 256, 0, stream>>>(Wv, Wb, W8);
    gemm8<0><<<dim3(16, 16), 512, 0, stream>>>(
        xb, Wb, Wb, Wb, bv, bv, bv, Vb, Vb, Vb);

    rope_table_k<<<(cB * cS * 64) / 256, 256, 0, stream>>>(pos, cosT, sinT);
    rope_apply<<<(2 * R8) / 256, 256, 0, stream>>>(Qb, Kb, cosT, sinT);
    transpose_v<<<dim3(cS / 32, cHD / 32, cB * cNH), 256, 0, stream>>>(Vb, Vt);
    attn_kernel<<<dim3(cS / 128, cB * cNH), 256, 0, stream>>>(Qb, Kb, Vt, Ab);

    cvt_bf16<<<W8 / 256, 256, 0, stream>>>(Wo, Wb, W8);
    gemm8<1><<<dim3(16, 16), 512, 0, stream>>>(
        Ab, Wb, Wb, Wb, bo, bo, bo, out, out, out);
  }
}